// Round 3
// baseline (181.251 us; speedup 1.0000x reference)
//
#include <hip/hip_runtime.h>

#define K 3

// Knot value at index j, computed on the fly from sorted x:
// t[0..K]=x[0]; t[j]= (x[j-3]+x[j-2]+x[j-1])/3 for K<j<N; t[j>=N]=x[N-1].
__device__ __forceinline__ float tfun(const float* __restrict__ x, int j, int N) {
    if (j <= K) return x[0];
    if (j >= N) return x[N - 1];
    return (x[j - 3] + x[j - 2] + x[j - 1]) / 3.0f;
}

// Windowed Cox-de Boor with safe_div (0-den -> 0) semantics, exactly mirroring
// the reference recursion on the 4-wide nonzero window [j0-K, j0].
__device__ __forceinline__ float4 deboor(const float* __restrict__ x, float xi,
                                         int j0, int N) {
    int c0 = j0 - K;
    float b[K + 2];
    #pragma unroll
    for (int w = 0; w < K + 2; ++w) b[w] = 0.f;
    b[K] = 1.f;
    #pragma unroll
    for (int d = 1; d <= K; ++d) {
        float nb[K + 1];
        #pragma unroll
        for (int w = 0; w <= K; ++w) {
            int j = c0 + w;
            float tj   = tfun(x, j, N);
            float tjd  = tfun(x, j + d, N);
            float tj1  = tfun(x, j + 1, N);
            float tjd1 = tfun(x, j + d + 1, N);
            float denL = tjd - tj;
            float L = (denL == 0.f) ? 0.f : (xi - tj) / denL;
            float denR = tjd1 - tj1;
            float R = (denR == 0.f) ? 0.f : (tjd1 - xi) / denR;
            nb[w] = L * b[w] + R * b[w + 1];
        }
        #pragma unroll
        for (int w = 0; w <= K; ++w) b[w] = nb[w];
    }
    return make_float4(b[0], b[1], b[2], b[3]);
}

// One fused kernel: blocks [0,N) write B rows (+first 17 also write knots),
// blocks [N,2N) write BTB rows. Every output byte written exactly once,
// no workspace, no inter-kernel dependencies.
__global__ __launch_bounds__(256) void fused(const float* __restrict__ x,
                                             const float* __restrict__ s_ptr,
                                             float* __restrict__ out_knots,
                                             float* __restrict__ outB,
                                             float* __restrict__ outBTB, int N) {
    int bid = blockIdx.x;
    int tid = threadIdx.x;
    int nk = N + K + 1;
    int fpr = N >> 2;   // float4 per row

    // knots side-duty (blocks 0..ceil(nk/256)-1)
    if (bid * 256 < nk) {
        int idx = bid * 256 + tid;
        if (idx < nk) out_knots[idx] = tfun(x, idx, N);
    }

    if (bid < N) {
        // ---- B row i ----
        int i = bid;
        float xi = x[i];
        int lo = 0, hi = nk;
        while (lo < hi) { int mid = (lo + hi) >> 1; if (tfun(x, mid, N) <= xi) lo = mid + 1; else hi = mid; }
        int j0 = lo - 1;
        if (j0 > N - 1) j0 = N - 1;   // x >= t[-2] override -> last basis column
        if (j0 < K) j0 = K;
        int c0 = j0 - K;
        float4 v4 = deboor(x, xi, j0, N);

        float4* rowp = (float4*)(outB + (long long)i * N);
        int fw0 = c0 >> 2, fw1 = (c0 + K) >> 2;
        for (int f = tid; f < fpr; f += 256) {
            float4 z = make_float4(0.f, 0.f, 0.f, 0.f);
            if (f == fw0 || f == fw1) {
                int e0 = f * 4;
                float e[4];
                #pragma unroll
                for (int l = 0; l < 4; ++l) {
                    int d = e0 + l - c0;
                    e[l] = (d == 0) ? v4.x : (d == 1) ? v4.y : (d == 2) ? v4.z
                         : (d == 3) ? v4.w : 0.f;
                }
                z = make_float4(e[0], e[1], e[2], e[3]);
            }
            rowp[f] = z;
        }
    } else {
        // ---- BTB row ci ----
        int ci = bid - N;
        // contributing rows r: j0[r] in [ci, ci+K]  <=>  x[r] in [t(ci), t(ci+K+1))
        float tlo = tfun(x, ci, N);
        int lo = 0, hi = N;
        while (lo < hi) { int mid = (lo + hi) >> 1; if (x[mid] < tlo) lo = mid + 1; else hi = mid; }
        int rlo = lo;
        int rhi, tgt = ci + K + 1;
        if (tgt > N - 1) {
            rhi = N;   // clamped top: every remaining row qualifies
        } else {
            float thi = tfun(x, tgt, N);
            hi = N;    // x sorted, thi >= tlo -> keep lo
            while (lo < hi) { int mid = (lo + hi) >> 1; if (x[mid] < thi) lo = mid + 1; else hi = mid; }
            rhi = lo;
        }
        int jhi = ci + K; if (jhi > N - 1) jhi = N - 1;

        float acc[2 * K + 1];
        #pragma unroll
        for (int a = 0; a < 2 * K + 1; ++a) acc[a] = 0.f;

        for (int r = rlo; r < rhi; ++r) {
            float xr = x[r];
            // j0 for row r lies in [ci, jhi] (<=4 candidates): scan down
            int j0r = jhi;
            #pragma unroll
            for (int it = 0; it < K; ++it)
                if (j0r > ci && tfun(x, j0r, N) > xr) --j0r;
            float4 v4 = deboor(x, xr, j0r, N);
            int wi = ci - (j0r - K);                     // in [0, K]
            float v = (wi == 0) ? v4.x : (wi == 1) ? v4.y : (wi == 2) ? v4.z : v4.w;
            #pragma unroll
            for (int o = -K; o <= K; ++o) {
                int wj = wi + o;
                float w = (wj == 0) ? v4.x : (wj == 1) ? v4.y : (wj == 2) ? v4.z
                        : (wj == 3) ? v4.w : 0.f;
                acc[o + K] += v * w;                     // acc index static
            }
        }
        acc[K] += *s_ptr;

        float4* rowp = (float4*)(outBTB + (long long)ci * N);
        int wlo = ci - K; if (wlo < 0) wlo = 0;
        int whi = ci + K; if (whi > N - 1) whi = N - 1;
        int fw0 = wlo >> 2, fw1 = whi >> 2;
        for (int f = tid; f < fpr; f += 256) {
            float4 z = make_float4(0.f, 0.f, 0.f, 0.f);
            if (f >= fw0 && f <= fw1) {
                int e0 = f * 4;
                float e[4];
                #pragma unroll
                for (int l = 0; l < 4; ++l) {
                    int d = e0 + l - ci;   // diagonal offset, want [-3, 3]
                    e[l] = (d == -3) ? acc[0] : (d == -2) ? acc[1] : (d == -1) ? acc[2]
                         : (d ==  0) ? acc[3] : (d ==  1) ? acc[4] : (d ==  2) ? acc[5]
                         : (d ==  3) ? acc[6] : 0.f;
                }
                z = make_float4(e[0], e[1], e[2], e[3]);
            }
            rowp[f] = z;
        }
    }
}

extern "C" void kernel_launch(void* const* d_in, const int* in_sizes, int n_in,
                              void* d_out, int out_size, void* d_ws, size_t ws_size,
                              hipStream_t stream) {
    const float* x = (const float*)d_in[0];
    const float* s = (const float*)d_in[1];
    int N = in_sizes[0];            // 4096
    int nk = N + K + 1;             // 4100

    float* out = (float*)d_out;
    float* out_knots = out;
    float* out_B = out + nk;                       // byte offset 16400 -> 16B aligned
    float* out_BTB = out_B + (long long)N * N;

    fused<<<2 * N, 256, 0, stream>>>(x, s, out_knots, out_B, out_BTB, N);
}

// Round 4
// 45.795 us; speedup vs baseline: 3.9579x; 3.9579x over previous
//
#include <hip/hip_runtime.h>

#define K 3

// Knot value at index j, computed on the fly from sorted x:
// t[0..K]=x[0]; t[j]=(x[j-3]+x[j-2]+x[j-1])/3 for K<j<N; t[j>=N]=x[N-1].
// Monotone nondecreasing in j. Same summation order as the reference.
__device__ __forceinline__ float tfun(const float* __restrict__ x, int j, int N) {
    if (j <= K) return x[0];
    if (j >= N) return x[N - 1];
    return (x[j - 3] + x[j - 2] + x[j - 1]) / 3.0f;
}

// Knot interval without binary search: t[i+1] <= x[i] (avg of values <= x[i])
// and t[i+4] > x[i] (avg of values >= x[i+1]), so j0 in {i+1,i+2,i+3}; then the
// reference's top-edge override / degree clamp = clamp to [K, N-1].
__device__ __forceinline__ int j0_of(const float* __restrict__ x, int i, int N) {
    float xi = x[i];
    int j0 = i + 1;
    if (tfun(x, i + 2, N) <= xi) j0 = i + 2;
    if (tfun(x, i + 3, N) <= xi) j0 = i + 3;
    if (j0 > N - 1) j0 = N - 1;
    if (j0 < K) j0 = K;
    return j0;
}

// Windowed Cox-de Boor with safe_div (0-den -> 0) semantics, exactly mirroring
// the reference recursion on the 4-wide nonzero window [j0-K, j0].
__device__ __forceinline__ float4 deboor(const float* __restrict__ x, float xi,
                                         int j0, int N) {
    int c0 = j0 - K;
    float b[K + 2];
    #pragma unroll
    for (int w = 0; w < K + 2; ++w) b[w] = 0.f;
    b[K] = 1.f;
    #pragma unroll
    for (int d = 1; d <= K; ++d) {
        float nb[K + 1];
        #pragma unroll
        for (int w = 0; w <= K; ++w) {
            int j = c0 + w;
            float tj   = tfun(x, j, N);
            float tjd  = tfun(x, j + d, N);
            float tj1  = tfun(x, j + 1, N);
            float tjd1 = tfun(x, j + d + 1, N);
            float denL = tjd - tj;
            float L = (denL == 0.f) ? 0.f : (xi - tj) / denL;
            float denR = tjd1 - tj1;
            float R = (denR == 0.f) ? 0.f : (tjd1 - xi) / denR;
            nb[w] = L * b[w] + R * b[w + 1];
        }
        #pragma unroll
        for (int w = 0; w <= K; ++w) b[w] = nb[w];
    }
    return make_float4(b[0], b[1], b[2], b[3]);
}

#define B1 64
#define HALO 4            // rows below block start; +5 above -> 73 LDS entries

// K1: all precompute in one launch. Thread i: knots, j0[i], vals4[i] (via LDS
// share with halo), and the 7-wide band column i of B^T B (+s on diagonal).
// Contributing rows for column ci satisfy j0[r] in [ci, ci+K], and since
// j0[r] in {r+1,r+2,r+3} (clamped), they lie within r in [ci-3, ci+5].
__global__ __launch_bounds__(B1) void k1_precompute(const float* __restrict__ x,
                                                    const float* __restrict__ s_ptr,
                                                    float* __restrict__ out_knots,
                                                    float* __restrict__ vals,
                                                    int* __restrict__ j0arr,
                                                    float* __restrict__ band, int N) {
    __shared__ float4 lv[73];
    __shared__ int lj[73];
    int t = threadIdx.x;
    int bs = blockIdx.x * B1;

    for (int k = t; k < 73; k += B1) {
        int rb = bs - HALO + k;
        if (rb >= 0 && rb < N) {
            int j0 = j0_of(x, rb, N);
            lj[k] = j0;
            lv[k] = deboor(x, x[rb], j0, N);
        } else {
            lj[k] = -1000000;                 // never passes the window test
            lv[k] = make_float4(0.f, 0.f, 0.f, 0.f);
        }
    }
    __syncthreads();

    int i = bs + t;
    if (i >= N) return;

    out_knots[i] = tfun(x, i, N);
    if (i < K + 1) out_knots[N + i] = x[N - 1];   // knots N..N+K

    int kk = t + HALO;
    int j0i = lj[kk];
    float4 v4i = lv[kk];
    j0arr[i] = j0i;
    *(float4*)(vals + 4 * i) = v4i;

    float acc[2 * K + 1];
    #pragma unroll
    for (int a = 0; a < 2 * K + 1; ++a) acc[a] = 0.f;

    #pragma unroll
    for (int d = -3; d <= 5; ++d) {               // candidate rows r = i + d
        int k2 = kk + d;                          // in [t+1, t+9] ⊂ [0,73)
        int j0r = lj[k2];
        if (j0r < i || j0r > i + K) continue;     // row doesn't touch column i
        float4 w4 = lv[k2];
        int wi = i - (j0r - K);                   // in [0, K]
        float v = (wi == 0) ? w4.x : (wi == 1) ? w4.y : (wi == 2) ? w4.z : w4.w;
        #pragma unroll
        for (int o = -K; o <= K; ++o) {
            int wj = wi + o;
            float w = (wj == 0) ? w4.x : (wj == 1) ? w4.y : (wj == 2) ? w4.z
                    : (wj == 3) ? w4.w : 0.f;
            acc[o + K] += v * w;                  // static acc index
        }
    }
    acc[K] += *s_ptr;

    *(float4*)(band + i * 8)     = make_float4(acc[0], acc[1], acc[2], acc[3]);
    *(float4*)(band + i * 8 + 4) = make_float4(acc[4], acc[5], acc[6], 0.f);
}

// K2: big streaming writer (proven in round 2). One block per output row;
// reads ~24 L2-hot bytes of precomputed tables, streams coalesced float4s.
__global__ __launch_bounds__(256) void k2_write(const float* __restrict__ vals,
                                                const int* __restrict__ j0arr,
                                                const float* __restrict__ band,
                                                float* __restrict__ outB,
                                                float* __restrict__ outBTB, int N) {
    int bid = blockIdx.x;
    int tid = threadIdx.x;
    int fpr = N >> 2;   // float4 per row

    if (bid < N) {
        int i = bid;
        int c0 = j0arr[i] - K;
        float4 v4 = *(const float4*)(vals + i * 4);
        float4* rowp = (float4*)(outB + (long long)i * N);
        int fw0 = c0 >> 2, fw1 = (c0 + K) >> 2;
        for (int f = tid; f < fpr; f += 256) {
            float4 z = make_float4(0.f, 0.f, 0.f, 0.f);
            if (f == fw0 || f == fw1) {
                int e0 = f * 4;
                float e[4];
                #pragma unroll
                for (int l = 0; l < 4; ++l) {
                    int d = e0 + l - c0;
                    e[l] = (d == 0) ? v4.x : (d == 1) ? v4.y : (d == 2) ? v4.z
                         : (d == 3) ? v4.w : 0.f;
                }
                z = make_float4(e[0], e[1], e[2], e[3]);
            }
            rowp[f] = z;
        }
    } else {
        int ci = bid - N;
        float4 b0 = *(const float4*)(band + ci * 8);       // offsets -3..0
        float4 b1 = *(const float4*)(band + ci * 8 + 4);   // offsets  1..3
        float4* rowp = (float4*)(outBTB + (long long)ci * N);
        int wlo = ci - K; if (wlo < 0) wlo = 0;
        int whi = ci + K; if (whi > N - 1) whi = N - 1;
        int fw0 = wlo >> 2, fw1 = whi >> 2;
        for (int f = tid; f < fpr; f += 256) {
            float4 z = make_float4(0.f, 0.f, 0.f, 0.f);
            if (f >= fw0 && f <= fw1) {
                int e0 = f * 4;
                float e[4];
                #pragma unroll
                for (int l = 0; l < 4; ++l) {
                    int d = e0 + l - ci;   // diagonal offset in [-3, 3]
                    e[l] = (d == -3) ? b0.x : (d == -2) ? b0.y : (d == -1) ? b0.z
                         : (d ==  0) ? b0.w : (d ==  1) ? b1.x : (d ==  2) ? b1.y
                         : (d ==  3) ? b1.z : 0.f;
                }
                z = make_float4(e[0], e[1], e[2], e[3]);
            }
            rowp[f] = z;
        }
    }
}

extern "C" void kernel_launch(void* const* d_in, const int* in_sizes, int n_in,
                              void* d_out, int out_size, void* d_ws, size_t ws_size,
                              hipStream_t stream) {
    const float* x = (const float*)d_in[0];
    const float* s = (const float*)d_in[1];
    int N = in_sizes[0];            // 4096
    int nk = N + K + 1;             // 4100

    float* out = (float*)d_out;
    float* out_knots = out;
    float* out_B = out + nk;                       // byte offset 16400 -> 16B aligned
    float* out_BTB = out_B + (long long)N * N;

    // workspace layout (all 16B-aligned): band (N*8 f) | vals (N*4 f) | j0 (N i)
    float* band_ws = (float*)d_ws;
    float* vals_ws = band_ws + (long long)N * 8;
    int* j0_ws = (int*)(vals_ws + (long long)N * 4);

    k1_precompute<<<(N + B1 - 1) / B1, B1, 0, stream>>>(x, s, out_knots,
                                                        vals_ws, j0_ws, band_ws, N);
    k2_write<<<2 * N, 256, 0, stream>>>(vals_ws, j0_ws, band_ws, out_B, out_BTB, N);
}